// Round 15
// baseline (325.091 us; speedup 1.0000x reference)
//
#include <hip/hip_runtime.h>
#include <hip/hip_bf16.h>

// Problem shapes (fixed by setup_inputs)
#define B_    1024
#define D_    768
#define POOL_ 100
#define KPAD  128                        // pool padded for transposed layout
#define PLEN_ 8
#define TOPK_ 3
#define EK_ELEMS (B_ * 4 * D_)           // 3,145,728
#define XB_ELEMS (B_ * 197 * D_)         // 154,976,256
#define XB_F4    (XB_ELEMS / 4)          // 38,744,064 float4s

#define BT 8                             // b-rows per score block
#define SCORE_BLOCKS (B_ / BT)           // 128
#define THREADS 512
#define COPY_BLOCKS  4096                // R7-proven copy config
#define NBLOCKS (SCORE_BLOCKS + COPY_BLOCKS)
#define REL_TARGET (100u * 512u)         // prep release: 100 blocks x 512 threads

typedef float  f4_t __attribute__((ext_vector_type(4)));
typedef double d2_t __attribute__((ext_vector_type(2)));

// ---------------------------------------------------------------------------
// ONE kernel. Roles:
//  blocks [0,128):  score. Blocks 0..99 FIRST prep pool row k=blockIdx.x
//    (softmax(A[k]) f64 + K-norm -> W_T[d][k] = {sm*nK, sm^2}), then
//    per-thread RELEASE adds (fire-and-forget, wave-coalesced; R3's failure
//    was 20K *dependent* claims, not the release pattern itself). All score
//    blocks stage xq (f32 LDS), RELAXED-spin on the counter (no per-poll
//    cache inv), one ACQUIRE, then the R13 W loop + top-3 + gather.
//  blocks [128, 4224): plain grid-stride float4 copy (NT reverted: R14 A/B
//    showed NT-load costs +8 us).
// Single dispatch: saves prep dispatch + 2 gaps (~12 us vs R13).
// Score VALU is hidden under the copy; only HBM traffic + serial overhead
// move the total (R13/R14 lesson).
// ---------------------------------------------------------------------------
__global__ void __launch_bounds__(THREADS)
fused_kernel(const float* __restrict__ xq,
             const float* __restrict__ A,
             const float* __restrict__ K,
             const float* __restrict__ p,
             const f4_t* __restrict__ xb,
             float* __restrict__ out,
             d2_t* __restrict__ W_T,
             unsigned int* __restrict__ ctr) {
    const int t = threadIdx.x;

    if (blockIdx.x >= SCORE_BLOCKS) {
        // ---------------- copy role ----------------
        f4_t* __restrict__ dst = (f4_t*)(out + 2 * (size_t)EK_ELEMS);
        size_t i = (size_t)(blockIdx.x - SCORE_BLOCKS) * THREADS + t;
        const size_t stride = (size_t)COPY_BLOCKS * THREADS;
        for (; i < (size_t)XB_F4; i += stride)
            dst[i] = xb[i];
        return;
    }

    // ---------------- score role ----------------
    __shared__ float  s_xqf[BT][D_];         // 24 KB, f32 stage
    __shared__ d2_t   s_buf[BT][KPAD];       // 16 KB, reduction buffer (reused)
    __shared__ double s_aq[BT][KPAD];        // 8 KB
    __shared__ int    s_idx[BT][TOPK_];
    __shared__ double red8[8];

    const int wave = t >> 6, lane = t & 63;

    // ---- phase 0: prep row k = blockIdx.x (blocks 0..99 only) ----
    if (blockIdx.x < POOL_) {
        const int k = blockIdx.x;

        double m = -1e300;
        for (int d = t; d < D_; d += THREADS) m = fmax(m, (double)A[k * D_ + d]);
        #pragma unroll
        for (int off = 32; off >= 1; off >>= 1) m = fmax(m, __shfl_xor(m, off));
        if (lane == 0) red8[wave] = m;
        __syncthreads();
        {
            double mm = red8[0];
            #pragma unroll
            for (int i = 1; i < 8; ++i) mm = fmax(mm, red8[i]);
            m = mm;
        }
        __syncthreads();

        double s = 0.0;
        for (int d = t; d < D_; d += THREADS) s += exp((double)A[k * D_ + d] - m);
        #pragma unroll
        for (int off = 32; off >= 1; off >>= 1) s += __shfl_xor(s, off);
        if (lane == 0) red8[wave] = s;
        __syncthreads();
        {
            double ssum = 0.0;
            #pragma unroll
            for (int i = 0; i < 8; ++i) ssum += red8[i];
            s = ssum;
        }
        __syncthreads();

        double ss = 0.0;
        for (int d = t; d < D_; d += THREADS) {
            double v = (double)K[k * D_ + d];
            ss += v * v;
        }
        #pragma unroll
        for (int off = 32; off >= 1; off >>= 1) ss += __shfl_xor(ss, off);
        if (lane == 0) red8[wave] = ss;
        __syncthreads();
        {
            double sst = 0.0;
            #pragma unroll
            for (int i = 0; i < 8; ++i) sst += red8[i];
            ss = sst;
        }
        const double n = fmax(sqrt(ss), 1e-12);

        for (int d = t; d < D_; d += THREADS) {
            const double smd = exp((double)A[k * D_ + d] - m) / s;
            W_T[(size_t)d * KPAD + k] = d2_t{smd * ((double)K[k * D_ + d] / n),
                                             smd * smd};
        }
        // per-thread release: orders this thread's W stores before the add
        __hip_atomic_fetch_add(ctr, 1u, __ATOMIC_RELEASE,
                               __HIP_MEMORY_SCOPE_AGENT);
        __syncthreads();   // red8 done before any reuse; also cleans phase
    }

    const int b0    = blockIdx.x * BT;
    const int klane = t & (KPAD - 1);
    const int dq    = t >> 7;                // 0..3, wave-uniform

    // stage xq while other blocks finish prep
    for (int i = t; i < BT * D_; i += THREADS)
        s_xqf[i / D_][i % D_] = xq[(size_t)(b0 + i / D_) * D_ + (i % D_)];

    // wait for all 100 prep rows (relaxed poll, one acquire at the end)
    if (t == 0) {
        while (__hip_atomic_load(ctr, __ATOMIC_RELAXED,
                                 __HIP_MEMORY_SCOPE_AGENT) < REL_TARGET)
            __builtin_amdgcn_s_sleep(32);
        (void)__hip_atomic_load(ctr, __ATOMIC_ACQUIRE,
                                __HIP_MEMORY_SCOPE_AGENT);
    }
    __syncthreads();   // covers s_xqf staging + W visibility for all threads

    double dot[BT], sq[BT];
    #pragma unroll
    for (int bl = 0; bl < BT; ++bl) { dot[bl] = 0.0; sq[bl] = 0.0; }

    const int dbeg = dq * (D_ / 4);
    #pragma unroll 4
    for (int i = 0; i < D_ / 4; ++i) {
        const int d = dbeg + i;
        const d2_t w = W_T[(size_t)d * KPAD + klane];
        #pragma unroll
        for (int bl = 0; bl < BT; ++bl) {
            const double x = (double)s_xqf[bl][d];   // bcast ds_read + cvt
            dot[bl] += x * w.x;
            sq[bl]  += (x * x) * w.y;
        }
    }

    // 3 reduction rounds through one buffer: dq==r writes, dq==0 accumulates
    #pragma unroll
    for (int r = 1; r < 4; ++r) {
        if (dq == r) {
            #pragma unroll
            for (int bl = 0; bl < BT; ++bl)
                s_buf[bl][klane] = d2_t{dot[bl], sq[bl]};
        }
        __syncthreads();
        if (dq == 0) {
            #pragma unroll
            for (int bl = 0; bl < BT; ++bl) {
                dot[bl] += s_buf[bl][klane].x;
                sq[bl]  += s_buf[bl][klane].y;
            }
        }
        __syncthreads();
    }
    if (dq == 0) {
        #pragma unroll
        for (int bl = 0; bl < BT; ++bl)
            s_aq[bl][klane] = dot[bl] / fmax(sqrt(sq[bl]), 1e-12);
    }
    __syncthreads();

    if (wave < 4) {
        // wave w: top-3 for rows w and w+4; tie -> lowest index (lax.top_k)
        #pragma unroll
        for (int half = 0; half < 2; ++half) {
            const int bl = wave + half * 4;
            double v0 = s_aq[bl][lane];                              // lane<64<100
            double v1 = (lane + 64 < POOL_) ? s_aq[bl][lane + 64] : -1e300;
            #pragma unroll
            for (int r = 0; r < TOPK_; ++r) {
                double v; int ki;
                if (v0 >= v1) { v = v0; ki = lane; }
                else          { v = v1; ki = lane + 64; }
                #pragma unroll
                for (int off = 32; off >= 1; off >>= 1) {
                    double ov = __shfl_xor(v, off);
                    int    oi = __shfl_xor(ki, off);
                    if (ov > v || (ov == v && oi < ki)) { v = ov; ki = oi; }
                }
                if (lane == 0) s_idx[bl][r] = ki;
                if (ki == lane)      v0 = -1e300;
                if (ki == lane + 64) v1 = -1e300;
            }
        }
    }
    __syncthreads();

    // gather: BT rows x 8 prompt-rows x 192 float4 = 12288 units / 512 threads
    for (int w = t; w < BT * PLEN_ * 192; w += THREADS) {
        const int bl  = w / (PLEN_ * 192);
        const int rem = w % (PLEN_ * 192);
        const int j = rem / 192, c = rem % 192;
        const int i0 = s_idx[bl][0], i1 = s_idx[bl][1], i2 = s_idx[bl][2];
        const int b = b0 + bl;
        const f4_t* __restrict__ q0 = (const f4_t*)(p + (size_t)(j * POOL_ + i0) * D_);
        const f4_t* __restrict__ q1 = (const f4_t*)(p + (size_t)(j * POOL_ + i1) * D_);
        const f4_t* __restrict__ q2 = (const f4_t*)(p + (size_t)(j * POOL_ + i2) * D_);
        f4_t v = q0[c] + q1[c] + q2[c];
        float* dst = (j < 4) ? out + ((size_t)b * 4 + j) * D_
                             : out + EK_ELEMS + ((size_t)b * 4 + (j - 4)) * D_;
        ((f4_t*)dst)[c] = v;
    }
}

extern "C" void kernel_launch(void* const* d_in, const int* in_sizes, int n_in,
                              void* d_out, int out_size, void* d_ws, size_t ws_size,
                              hipStream_t stream) {
    const float* x_querry = (const float*)d_in[0];   // (1024, 768)
    const float* x_block  = (const float*)d_in[1];   // (1024, 197, 768)
    const float* K        = (const float*)d_in[2];   // (100, 768)
    const float* A        = (const float*)d_in[3];   // (100, 768)
    const float* p        = (const float*)d_in[4];   // (8, 100, 768)
    // d_in[5] = l (unused)

    float* out = (float*)d_out;

    // workspace: W_T interleaved {u,v} double2 [768][128], then counter
    d2_t* W_T = (d2_t*)d_ws;                               // 1,572,864 B
    unsigned int* ctr = (unsigned int*)(W_T + (size_t)D_ * KPAD);

    hipMemsetAsync(ctr, 0, sizeof(unsigned int), stream);
    fused_kernel<<<NBLOCKS, THREADS, 0, stream>>>(x_querry, A, K, p,
                                                  (const f4_t*)x_block, out,
                                                  W_T, ctr);
}

// Round 16
// 242.285 us; speedup vs baseline: 1.3418x; 1.3418x over previous
//
#include <hip/hip_runtime.h>
#include <hip/hip_bf16.h>

// Problem shapes (fixed by setup_inputs)
#define B_    1024
#define D_    768
#define POOL_ 100
#define KPAD  128                        // pool padded for transposed layout
#define PLEN_ 8
#define TOPK_ 3
#define EK_ELEMS (B_ * 4 * D_)           // 3,145,728
#define XB_ELEMS (B_ * 197 * D_)         // 154,976,256
#define XB_F4    (XB_ELEMS / 4)          // 38,744,064 float4s

#define BT 8                             // b-rows per score block
#define SCORE_BLOCKS (B_ / BT)           // 128
#define THREADS 512
#define COPY_BLOCKS  4096                // R7-proven copy config
#define NBLOCKS (SCORE_BLOCKS + COPY_BLOCKS)

typedef float  f4_t __attribute__((ext_vector_type(4)));
typedef double d2_t __attribute__((ext_vector_type(2)));

// ---------------------------------------------------------------------------
// Kernel 1: prep (separate dispatch — R15 lesson: in-kernel sync costs ~78 us;
// a tiny serial dispatch costs ~8+gap). For k<100: sm = softmax(A[k,:]),
// n = ||K[k,:]||, write W_T[d][k] = {sm*K/n, sm^2} (double2, k-contiguous).
// For k in [100,128): zero pad columns.
// ---------------------------------------------------------------------------
__global__ void prep_kernel(const float* __restrict__ A, const float* __restrict__ K,
                            d2_t* __restrict__ W_T) {
    const int k = blockIdx.x;
    const int t = threadIdx.x;

    if (k >= POOL_) {
        for (int d = t; d < D_; d += 256)
            W_T[(size_t)d * KPAD + k] = d2_t{0.0, 0.0};
        return;
    }

    const int wave = t >> 6, lane = t & 63;
    __shared__ double red[4];

    double m = -1e300;
    for (int d = t; d < D_; d += 256) m = fmax(m, (double)A[k * D_ + d]);
    #pragma unroll
    for (int off = 32; off >= 1; off >>= 1) m = fmax(m, __shfl_xor(m, off));
    if (lane == 0) red[wave] = m;
    __syncthreads();
    m = fmax(fmax(red[0], red[1]), fmax(red[2], red[3]));
    __syncthreads();

    double s = 0.0;
    for (int d = t; d < D_; d += 256) s += exp((double)A[k * D_ + d] - m);
    #pragma unroll
    for (int off = 32; off >= 1; off >>= 1) s += __shfl_xor(s, off);
    if (lane == 0) red[wave] = s;
    __syncthreads();
    s = red[0] + red[1] + red[2] + red[3];
    __syncthreads();

    double ss = 0.0;
    for (int d = t; d < D_; d += 256) {
        double v = (double)K[k * D_ + d];
        ss += v * v;
    }
    #pragma unroll
    for (int off = 32; off >= 1; off >>= 1) ss += __shfl_xor(ss, off);
    if (lane == 0) red[wave] = ss;
    __syncthreads();
    ss = red[0] + red[1] + red[2] + red[3];
    const double n = fmax(sqrt(ss), 1e-12);

    for (int d = t; d < D_; d += 256) {
        const double smd = exp((double)A[k * D_ + d] - m) / s;
        W_T[(size_t)d * KPAD + k] = d2_t{smd * ((double)K[k * D_ + d] / n),
                                         smd * smd};
    }
}

// ---------------------------------------------------------------------------
// Kernel 2 (fused score + copy) — exact R13 champion (247.1 us) + ONE change:
//   copy-role STORES are nontemporal (skip L2 write-allocate), loads plain.
//   R14 A/B: NT-load hurt (+7.7 us) -> loads want L2/L3 absorption.
//   Theory: the 620 MB store stream's write-allocate is half the copy's L2
//   footprint and pure pollution (never re-read); NT-store halves pollution
//   so W (1.5 MB) survives between score-block reads, cutting the ~192 MB
//   W re-fetch from HBM.
// ---------------------------------------------------------------------------
__global__ void __launch_bounds__(THREADS)
fused_kernel(const float* __restrict__ xq,
             const d2_t* __restrict__ W_T,
             const float* __restrict__ p,
             const f4_t* __restrict__ xb,
             float* __restrict__ out) {
    const int t = threadIdx.x;

    if (blockIdx.x >= SCORE_BLOCKS) {
        // ---------------- copy role ----------------
        f4_t* __restrict__ dst = (f4_t*)(out + 2 * (size_t)EK_ELEMS);
        size_t i = (size_t)(blockIdx.x - SCORE_BLOCKS) * THREADS + t;
        const size_t stride = (size_t)COPY_BLOCKS * THREADS;
        for (; i < (size_t)XB_F4; i += stride) {
            f4_t v = xb[i];                            // plain load (R14)
            __builtin_nontemporal_store(v, &dst[i]);   // nt STORE only
        }
        return;
    }

    // ---------------- score role (identical to R13) ----------------
    __shared__ float  s_xqf[BT][D_];         // 24 KB, f32 stage
    __shared__ d2_t   s_buf[BT][KPAD];       // 16 KB, reduction buffer (reused)
    __shared__ double s_aq[BT][KPAD];        // 8 KB
    __shared__ int    s_idx[BT][TOPK_];

    const int b0    = blockIdx.x * BT;
    const int klane = t & (KPAD - 1);
    const int dq    = t >> 7;                // 0..3, wave-uniform

    for (int i = t; i < BT * D_; i += THREADS)
        s_xqf[i / D_][i % D_] = xq[(size_t)(b0 + i / D_) * D_ + (i % D_)];
    __syncthreads();

    double dot[BT], sq[BT];
    #pragma unroll
    for (int bl = 0; bl < BT; ++bl) { dot[bl] = 0.0; sq[bl] = 0.0; }

    const int dbeg = dq * (D_ / 4);
    #pragma unroll 4
    for (int i = 0; i < D_ / 4; ++i) {
        const int d = dbeg + i;
        const d2_t w = W_T[(size_t)d * KPAD + klane];
        #pragma unroll
        for (int bl = 0; bl < BT; ++bl) {
            const double x = (double)s_xqf[bl][d];   // bcast ds_read + cvt
            dot[bl] += x * w.x;
            sq[bl]  += (x * x) * w.y;
        }
    }

    // 3 reduction rounds through one buffer: dq==r writes, dq==0 accumulates
    #pragma unroll
    for (int r = 1; r < 4; ++r) {
        if (dq == r) {
            #pragma unroll
            for (int bl = 0; bl < BT; ++bl)
                s_buf[bl][klane] = d2_t{dot[bl], sq[bl]};
        }
        __syncthreads();
        if (dq == 0) {
            #pragma unroll
            for (int bl = 0; bl < BT; ++bl) {
                dot[bl] += s_buf[bl][klane].x;
                sq[bl]  += s_buf[bl][klane].y;
            }
        }
        __syncthreads();
    }
    if (dq == 0) {
        #pragma unroll
        for (int bl = 0; bl < BT; ++bl)
            s_aq[bl][klane] = dot[bl] / fmax(sqrt(sq[bl]), 1e-12);
    }
    __syncthreads();

    const int wave = t >> 6, lane = t & 63;
    if (wave < 4) {
        // wave w: top-3 for rows w and w+4; tie -> lowest index (lax.top_k)
        #pragma unroll
        for (int half = 0; half < 2; ++half) {
            const int bl = wave + half * 4;
            double v0 = s_aq[bl][lane];                              // lane<64<100
            double v1 = (lane + 64 < POOL_) ? s_aq[bl][lane + 64] : -1e300;
            #pragma unroll
            for (int r = 0; r < TOPK_; ++r) {
                double v; int ki;
                if (v0 >= v1) { v = v0; ki = lane; }
                else          { v = v1; ki = lane + 64; }
                #pragma unroll
                for (int off = 32; off >= 1; off >>= 1) {
                    double ov = __shfl_xor(v, off);
                    int    oi = __shfl_xor(ki, off);
                    if (ov > v || (ov == v && oi < ki)) { v = ov; ki = oi; }
                }
                if (lane == 0) s_idx[bl][r] = ki;
                if (ki == lane)      v0 = -1e300;
                if (ki == lane + 64) v1 = -1e300;
            }
        }
    }
    __syncthreads();

    // gather: BT rows x 8 prompt-rows x 192 float4 = 12288 units / 512 threads
    for (int w = t; w < BT * PLEN_ * 192; w += THREADS) {
        const int bl  = w / (PLEN_ * 192);
        const int rem = w % (PLEN_ * 192);
        const int j = rem / 192, c = rem % 192;
        const int i0 = s_idx[bl][0], i1 = s_idx[bl][1], i2 = s_idx[bl][2];
        const int b = b0 + bl;
        const f4_t* __restrict__ q0 = (const f4_t*)(p + (size_t)(j * POOL_ + i0) * D_);
        const f4_t* __restrict__ q1 = (const f4_t*)(p + (size_t)(j * POOL_ + i1) * D_);
        const f4_t* __restrict__ q2 = (const f4_t*)(p + (size_t)(j * POOL_ + i2) * D_);
        f4_t v = q0[c] + q1[c] + q2[c];
        float* dst = (j < 4) ? out + ((size_t)b * 4 + j) * D_
                             : out + EK_ELEMS + ((size_t)b * 4 + (j - 4)) * D_;
        ((f4_t*)dst)[c] = v;
    }
}

extern "C" void kernel_launch(void* const* d_in, const int* in_sizes, int n_in,
                              void* d_out, int out_size, void* d_ws, size_t ws_size,
                              hipStream_t stream) {
    const float* x_querry = (const float*)d_in[0];   // (1024, 768)
    const float* x_block  = (const float*)d_in[1];   // (1024, 197, 768)
    const float* K        = (const float*)d_in[2];   // (100, 768)
    const float* A        = (const float*)d_in[3];   // (100, 768)
    const float* p        = (const float*)d_in[4];   // (8, 100, 768)
    // d_in[5] = l (unused)

    float* out = (float*)d_out;

    // workspace: W_T interleaved {u,v} double2 [768][128]
    d2_t* W_T = (d2_t*)d_ws;                         // 1,572,864 B

    prep_kernel<<<KPAD, 256, 0, stream>>>(A, K, W_T);
    fused_kernel<<<NBLOCKS, THREADS, 0, stream>>>(x_querry, W_T, p,
                                                  (const f4_t*)x_block, out);
}